// Round 8
// baseline (80.168 us; speedup 1.0000x reference)
//
#include <hip/hip_runtime.h>
#include <hip/hip_bf16.h>

#define BSZ 4096
#define NSZ 8192
#define DD  128
#define GROUPS 16
#define TPB 8     // 64-col tiles per block (block covers 512 cols)
#define C2 14.426950408889634f   // 10 * log2(e): exp(10*s) = exp2(s*C2)

typedef __attribute__((ext_vector_type(8))) short bf16x8;
typedef __attribute__((ext_vector_type(4))) float f32x4;

// ---------------- Kernel 1: normalize rows of reps=[zjs; zis] -> bf16 ----------------
__global__ __launch_bounds__(256)
void norm_kernel(const float* __restrict__ zis,
                 const float* __restrict__ zjs,
                 __hip_bfloat16* __restrict__ rn) {
    const int row  = blockIdx.x * 4 + (threadIdx.x >> 6);
    const int lane = threadIdx.x & 63;
    const float* src = (row < BSZ) ? (zjs + (size_t)row * DD)
                                   : (zis + (size_t)(row - BSZ) * DD);
    float2 v = *(const float2*)(src + lane * 2);
    float ss = v.x * v.x + v.y * v.y;
    #pragma unroll
    for (int off = 32; off; off >>= 1) ss += __shfl_xor(ss, off);
    float inv = 1.0f / fmaxf(sqrtf(ss), 1e-8f);
    __hip_bfloat16 a = __float2bfloat16(v.x * inv);
    __hip_bfloat16 b = __float2bfloat16(v.y * inv);
    ushort2 pk;
    pk.x = *(const ushort*)&a;
    pk.y = *(const ushort*)&b;
    *(ushort2*)(rn + (size_t)row * DD + lane * 2) = pk;
}

// ---------------- Kernel 2: occupancy-first fused sim GEMM + exp + row sums ---------
// grid (GROUPS, 64): bi = blockIdx.y (128-row tile), g = blockIdx.x (512-col group).
// 256 threads = 4 waves; wave w owns the 32-row granule rg = bi*4+w. Block loops
// over TPB=8 col-tiles of 64. All 4 waves load IDENTICAL B fragments (L1 reuse;
// per-tile __syncthreads keeps them in lockstep). Per-wave live set ~110 VGPR ->
// 4 waves/SIMD. No LDS staging, no atomics. Row sums accumulate in registers
// across all tiles; disjoint rows per wave -> direct partials store, no LDS.
__global__ __launch_bounds__(256)
void sim_lse_kernel(const __hip_bfloat16* __restrict__ rn,
                    float* __restrict__ partials,
                    float* __restrict__ pos) {
    const int g   = blockIdx.x;      // 0..GROUPS-1
    const int bi  = blockIdx.y;      // 0..63
    const int tid = threadIdx.x;
    const int wid  = tid >> 6;       // 0..3
    const int lane = tid & 63;
    const int l15  = lane & 15;
    const int kg   = lane >> 4;      // 0..3

    const int rg  = bi * 4 + wid;               // 32-row granule, 0..255
    const int dgc = rg >> 1;                    // diagonal 64-col granule
    const int pgc = ((rg >> 1) + 64) & 127;     // positive-partner granule
    const int nhm = rg & 1;                     // which 32-col half matches

    // ---- A fragments: this wave's 32 rows, kept in registers ----
    const char* abase = (const char*)rn + (size_t)(rg * 32 + l15) * 256;
    bf16x8 af[2][4];
    #pragma unroll
    for (int mf = 0; mf < 2; ++mf)
        #pragma unroll
        for (int kk = 0; kk < 4; ++kk)
            af[mf][kk] = *(const bf16x8*)(abase + mf * 16 * 256 + kk * 64 + kg * 16);

    float rsum[2][4] = {};

    for (int t = 0; t < TPB; ++t) {
        const int gc = g * TPB + t;             // 64-col granule, 0..127
        const char* bbase = (const char*)rn + (size_t)gc * 64 * 256;
        const bool isd = (gc == dgc);
        const bool isp = (gc == pgc);

        #pragma unroll
        for (int nh = 0; nh < 2; ++nh) {
            // ---- B fragments for this 32-col half (same for all 4 waves -> L1) ----
            bf16x8 bfr[2][4];
            #pragma unroll
            for (int nf2 = 0; nf2 < 2; ++nf2)
                #pragma unroll
                for (int kk = 0; kk < 4; ++kk)
                    bfr[nf2][kk] = *(const bf16x8*)(bbase
                        + (size_t)(nh * 32 + nf2 * 16 + l15) * 256 + kk * 64 + kg * 16);

            // ---- MFMA: 32 rows x 32 cols, K=128 ----
            f32x4 acc[2][2] = {};
            #pragma unroll
            for (int kk = 0; kk < 4; ++kk)
                #pragma unroll
                for (int mf = 0; mf < 2; ++mf)
                    #pragma unroll
                    for (int nf2 = 0; nf2 < 2; ++nf2)
                        acc[mf][nf2] = __builtin_amdgcn_mfma_f32_16x16x32_bf16(
                            af[mf][kk], bfr[nf2][kk], acc[mf][nf2], 0, 0, 0);

            // ---- lean epilogue: rsum += exp2(s*C2) ----
            #pragma unroll
            for (int mf = 0; mf < 2; ++mf)
                #pragma unroll
                for (int nf2 = 0; nf2 < 2; ++nf2)
                    #pragma unroll
                    for (int reg = 0; reg < 4; ++reg)
                        rsum[mf][reg] += exp2f(acc[mf][nf2][reg] * C2);

            // ---- rare fixups (wave-uniform): diag self-term, positive capture ----
            if (isd && nh == nhm) {
                #pragma unroll
                for (int mf = 0; mf < 2; ++mf)
                    #pragma unroll
                    for (int reg = 0; reg < 4; ++reg)
                        if (kg * 4 + reg == l15)
                            rsum[mf][reg] -= exp2f(acc[mf][mf][reg] * C2);
            }
            if (isp && nh == nhm) {
                #pragma unroll
                for (int mf = 0; mf < 2; ++mf)
                    #pragma unroll
                    for (int reg = 0; reg < 4; ++reg)
                        if (kg * 4 + reg == l15)
                            pos[rg * 32 + mf * 16 + l15] = acc[mf][mf][reg];
            }
        }
        __syncthreads();   // keep the 4 waves lockstepped for L1 B-reuse
    }

    // ---- row-sum reduce across the 16 l15-lanes; direct store (disjoint rows) ----
    #pragma unroll
    for (int mf = 0; mf < 2; ++mf)
        #pragma unroll
        for (int reg = 0; reg < 4; ++reg) {
            float v = rsum[mf][reg];
            v += __shfl_xor(v, 1);
            v += __shfl_xor(v, 2);
            v += __shfl_xor(v, 4);
            v += __shfl_xor(v, 8);
            if (l15 == 0)
                partials[(size_t)g * NSZ + rg * 32 + mf * 16 + kg * 4 + reg] = v;
        }
}

// ---------------- Kernel 3: final scalar reduction ----------------
__global__ __launch_bounds__(1024)
void reduce_kernel(const float* __restrict__ partials,
                   const float* __restrict__ pos,
                   float* __restrict__ out) {
    int tid = threadIdx.x;  // 1024; 8 rows each
    int base = tid * 8;
    float se[8] = {0.f, 0.f, 0.f, 0.f, 0.f, 0.f, 0.f, 0.f};
    #pragma unroll
    for (int gr = 0; gr < GROUPS; ++gr) {
        const float* p = partials + (size_t)gr * NSZ + base;
        float4 a = *(const float4*)(p);
        float4 b = *(const float4*)(p + 4);
        se[0] += a.x; se[1] += a.y; se[2] += a.z; se[3] += a.w;
        se[4] += b.x; se[5] += b.y; se[6] += b.z; se[7] += b.w;
    }
    float ce = 0.f, pt = 0.f;
    #pragma unroll
    for (int h = 0; h < 2; ++h) {
        float4 p4 = *(const float4*)(pos + base + h * 4);
        const float* pp = (const float*)&p4;
        #pragma unroll
        for (int q = 0; q < 4; ++q) {
            float s = se[h * 4 + q];
            ce += __logf(s) - pp[q] * 10.0f;
            pt += exp2f(pp[q] * C2) / s;
        }
    }
    #pragma unroll
    for (int off = 32; off; off >>= 1) {
        ce += __shfl_xor(ce, off);
        pt += __shfl_xor(pt, off);
    }
    __shared__ float lce[16], lpt[16];
    if ((tid & 63) == 0) { lce[tid >> 6] = ce; lpt[tid >> 6] = pt; }
    __syncthreads();
    if (tid == 0) {
        float CE = 0.f, PT = 0.f;
        #pragma unroll
        for (int w = 0; w < 16; ++w) { CE += lce[w]; PT += lpt[w]; }
        float loss = CE / (float)NSZ + 1.0f
                   - PT * ((float)BSZ / ((float)NSZ * (float)(NSZ - 1)));
        out[0] = loss;
    }
}

extern "C" void kernel_launch(void* const* d_in, const int* in_sizes, int n_in,
                              void* d_out, int out_size, void* d_ws, size_t ws_size,
                              hipStream_t stream) {
    const float* zis = (const float*)d_in[0];
    const float* zjs = (const float*)d_in[1];
    float* out = (float*)d_out;

    char* ws = (char*)d_ws;
    __hip_bfloat16* rn = (__hip_bfloat16*)ws;                       // 2 MB
    float* partials = (float*)(ws + 2 * 1024 * 1024);               // 512 KB
    float* pos      = (float*)(ws + 2 * 1024 * 1024 + 512 * 1024);  // 32 KB

    norm_kernel<<<NSZ / 4, 256, 0, stream>>>(zis, zjs, rn);

    dim3 grid(GROUPS, 64);
    sim_lse_kernel<<<grid, 256, 0, stream>>>(rn, partials, pos);

    reduce_kernel<<<1, 1024, 0, stream>>>(partials, pos, out);
}

// Round 9
// 79.726 us; speedup vs baseline: 1.0055x; 1.0055x over previous
//
#include <hip/hip_runtime.h>
#include <hip/hip_bf16.h>

#define BSZ 4096
#define NSZ 8192
#define DD  128
#define GROUPS 16
#define TPB 8     // 64-col tiles per block (block covers 512 cols)

typedef __attribute__((ext_vector_type(8))) short bf16x8;
typedef __attribute__((ext_vector_type(4))) float f32x4;

// ---------------- Kernel 1: normalize rows of reps=[zjs; zis] -> bf16 ----------------
__global__ __launch_bounds__(256)
void norm_kernel(const float* __restrict__ zis,
                 const float* __restrict__ zjs,
                 __hip_bfloat16* __restrict__ rn) {
    const int row  = blockIdx.x * 4 + (threadIdx.x >> 6);
    const int lane = threadIdx.x & 63;
    const float* src = (row < BSZ) ? (zjs + (size_t)row * DD)
                                   : (zis + (size_t)(row - BSZ) * DD);
    float2 v = *(const float2*)(src + lane * 2);
    float ss = v.x * v.x + v.y * v.y;
    #pragma unroll
    for (int off = 32; off; off >>= 1) ss += __shfl_xor(ss, off);
    float inv = 1.0f / fmaxf(sqrtf(ss), 1e-8f);
    __hip_bfloat16 a = __float2bfloat16(v.x * inv);
    __hip_bfloat16 b = __float2bfloat16(v.y * inv);
    ushort2 pk;
    pk.x = *(const ushort*)&a;
    pk.y = *(const ushort*)&b;
    *(ushort2*)(rn + (size_t)row * DD + lane * 2) = pk;
}

// ---------------- Kernel 2: fused sim GEMM + exp + row sums, pinned A-frags ---------
// grid (GROUPS, 64): bi = blockIdx.y (128-row tile), g = blockIdx.x (512-col group).
// 256 threads = 4 waves; wave w owns the 32-row granule rg = bi*4+w. Block loops
// over TPB=8 col-tiles of 64. A-fragments loaded ONCE and pinned in VGPRs via an
// opaque asm barrier (hipcc otherwise sinks the loads into the loop -- R7/R8
// showed VGPR=88/48 with per-iteration A reloads). All 4 waves load identical
// B fragments (L1 reuse, lockstepped by one barrier per tile). No LDS staging,
// no atomics; per-row partials stored directly (disjoint rows per wave).
__global__ __launch_bounds__(256)
void sim_lse_kernel(const __hip_bfloat16* __restrict__ rn,
                    float* __restrict__ partials,
                    float* __restrict__ pos) {
    const int g   = blockIdx.x;      // 0..GROUPS-1
    const int bi  = blockIdx.y;      // 0..63
    const int tid = threadIdx.x;
    const int wid  = tid >> 6;       // 0..3
    const int lane = tid & 63;
    const int l15  = lane & 15;
    const int kg   = lane >> 4;      // 0..3

    const int rg  = bi * 4 + wid;               // 32-row granule, 0..255
    const int dgc = rg >> 1;                    // diagonal 64-col granule
    const int pgc = ((rg >> 1) + 64) & 127;     // positive-partner granule
    const int nhm = rg & 1;                     // which 32-col half matches

    // ---- A fragments: this wave's 32 rows, loaded once and PINNED in VGPRs ----
    const char* abase = (const char*)rn + (size_t)(rg * 32 + l15) * 256;
    bf16x8 af[2][4];
    #pragma unroll
    for (int mf = 0; mf < 2; ++mf)
        #pragma unroll
        for (int kk = 0; kk < 4; ++kk)
            af[mf][kk] = *(const bf16x8*)(abase + mf * 16 * 256 + kk * 64 + kg * 16);
    // opacity barrier: compiler cannot rematerialize these -> stays in registers
    #pragma unroll
    for (int mf = 0; mf < 2; ++mf)
        #pragma unroll
        for (int kk = 0; kk < 4; ++kk)
            asm volatile("" : "+v"(af[mf][kk]));

    float rsum[2][4] = {};

    for (int t = 0; t < TPB; ++t) {
        const int gc = g * TPB + t;             // 64-col granule, 0..127
        const char* bbase = (const char*)rn + (size_t)gc * 64 * 256;
        const bool isd = (gc == dgc);
        const bool isp = (gc == pgc);

        #pragma unroll
        for (int nh = 0; nh < 2; ++nh) {
            // ---- B fragments for this 32-col half (same for all 4 waves -> L1) ----
            bf16x8 bfr[2][4];
            #pragma unroll
            for (int nf2 = 0; nf2 < 2; ++nf2)
                #pragma unroll
                for (int kk = 0; kk < 4; ++kk)
                    bfr[nf2][kk] = *(const bf16x8*)(bbase
                        + (size_t)(nh * 32 + nf2 * 16 + l15) * 256 + kk * 64 + kg * 16);

            // ---- MFMA: 32 rows x 32 cols, K=128 ----
            f32x4 acc[2][2] = {};
            #pragma unroll
            for (int kk = 0; kk < 4; ++kk)
                #pragma unroll
                for (int mf = 0; mf < 2; ++mf)
                    #pragma unroll
                    for (int nf2 = 0; nf2 < 2; ++nf2)
                        acc[mf][nf2] = __builtin_amdgcn_mfma_f32_16x16x32_bf16(
                            af[mf][kk], bfr[nf2][kk], acc[mf][nf2], 0, 0, 0);

            // ---- lean epilogue: rsum += exp(s*10) ----
            #pragma unroll
            for (int mf = 0; mf < 2; ++mf)
                #pragma unroll
                for (int nf2 = 0; nf2 < 2; ++nf2)
                    #pragma unroll
                    for (int reg = 0; reg < 4; ++reg)
                        rsum[mf][reg] += __expf(acc[mf][nf2][reg] * 10.0f);

            // ---- rare fixups (wave-uniform): diag self-term, positive capture ----
            if (isd && nh == nhm) {
                #pragma unroll
                for (int mf = 0; mf < 2; ++mf)
                    #pragma unroll
                    for (int reg = 0; reg < 4; ++reg)
                        if (kg * 4 + reg == l15)
                            rsum[mf][reg] -= __expf(acc[mf][mf][reg] * 10.0f);
            }
            if (isp && nh == nhm) {
                #pragma unroll
                for (int mf = 0; mf < 2; ++mf)
                    #pragma unroll
                    for (int reg = 0; reg < 4; ++reg)
                        if (kg * 4 + reg == l15)
                            pos[rg * 32 + mf * 16 + l15] = acc[mf][mf][reg];
            }
        }
        __syncthreads();   // keep the 4 waves lockstepped for L1 B-reuse
    }

    // ---- row-sum reduce across the 16 l15-lanes; direct store (disjoint rows) ----
    #pragma unroll
    for (int mf = 0; mf < 2; ++mf)
        #pragma unroll
        for (int reg = 0; reg < 4; ++reg) {
            float v = rsum[mf][reg];
            v += __shfl_xor(v, 1);
            v += __shfl_xor(v, 2);
            v += __shfl_xor(v, 4);
            v += __shfl_xor(v, 8);
            if (l15 == 0)
                partials[(size_t)g * NSZ + rg * 32 + mf * 16 + kg * 4 + reg] = v;
        }
}

// ---------------- Kernel 3: final scalar reduction ----------------
__global__ __launch_bounds__(1024)
void reduce_kernel(const float* __restrict__ partials,
                   const float* __restrict__ pos,
                   float* __restrict__ out) {
    int tid = threadIdx.x;  // 1024; 8 rows each
    int base = tid * 8;
    float se[8] = {0.f, 0.f, 0.f, 0.f, 0.f, 0.f, 0.f, 0.f};
    #pragma unroll
    for (int gr = 0; gr < GROUPS; ++gr) {
        const float* p = partials + (size_t)gr * NSZ + base;
        float4 a = *(const float4*)(p);
        float4 b = *(const float4*)(p + 4);
        se[0] += a.x; se[1] += a.y; se[2] += a.z; se[3] += a.w;
        se[4] += b.x; se[5] += b.y; se[6] += b.z; se[7] += b.w;
    }
    float ce = 0.f, pt = 0.f;
    #pragma unroll
    for (int h = 0; h < 2; ++h) {
        float4 p4 = *(const float4*)(pos + base + h * 4);
        const float* pp = (const float*)&p4;
        #pragma unroll
        for (int q = 0; q < 4; ++q) {
            float s = se[h * 4 + q];
            ce += __logf(s) - pp[q] * 10.0f;
            pt += __expf(pp[q] * 10.0f) / s;
        }
    }
    #pragma unroll
    for (int off = 32; off; off >>= 1) {
        ce += __shfl_xor(ce, off);
        pt += __shfl_xor(pt, off);
    }
    __shared__ float lce[16], lpt[16];
    if ((tid & 63) == 0) { lce[tid >> 6] = ce; lpt[tid >> 6] = pt; }
    __syncthreads();
    if (tid == 0) {
        float CE = 0.f, PT = 0.f;
        #pragma unroll
        for (int w = 0; w < 16; ++w) { CE += lce[w]; PT += lpt[w]; }
        float loss = CE / (float)NSZ + 1.0f
                   - PT * ((float)BSZ / ((float)NSZ * (float)(NSZ - 1)));
        out[0] = loss;
    }
}

extern "C" void kernel_launch(void* const* d_in, const int* in_sizes, int n_in,
                              void* d_out, int out_size, void* d_ws, size_t ws_size,
                              hipStream_t stream) {
    const float* zis = (const float*)d_in[0];
    const float* zjs = (const float*)d_in[1];
    float* out = (float*)d_out;

    char* ws = (char*)d_ws;
    __hip_bfloat16* rn = (__hip_bfloat16*)ws;                       // 2 MB
    float* partials = (float*)(ws + 2 * 1024 * 1024);               // 512 KB
    float* pos      = (float*)(ws + 2 * 1024 * 1024 + 512 * 1024);  // 32 KB

    norm_kernel<<<NSZ / 4, 256, 0, stream>>>(zis, zjs, rn);

    dim3 grid(GROUPS, 64);
    sim_lse_kernel<<<grid, 256, 0, stream>>>(rn, partials, pos);

    reduce_kernel<<<1, 1024, 0, stream>>>(partials, pos, out);
}